// Round 6
// baseline (1373.588 us; speedup 1.0000x reference)
//
#include <hip/hip_runtime.h>

typedef float f32x4 __attribute__((ext_vector_type(4)));
typedef uint  u32x4 __attribute__((ext_vector_type(4)));
typedef __bf16 bf16x8 __attribute__((ext_vector_type(8)));

constexpr int BATCH = 2;
constexpr int NNODE = 10000;
constexpr int NEDGE = 320000;
constexpr int D = 128;
constexpr int TOTN = BATCH * NNODE;    // 20000
constexpr int TOTE = BATCH * NEDGE;    // 640000

// ---- workspace layout (bytes) ----
constexpr size_t WS_CNT   = 0;           // u32 [20000]
constexpr size_t WS_OFF   = 80000;       // u32 [20000]
constexpr size_t WS_CUR   = 160000;      // u32 [20000]
constexpr size_t WS_ELIST = 240000;      // u32 [640000]
constexpr size_t WS_AGG   = 2800000;     // f32 [20000*128]
constexpr size_t WS_W1E   = 13040000;    // bf16 pack 98,304
constexpr size_t WS_W2E   = 13138304;    // 32,768
constexpr size_t WS_W1N   = 13171072;    // 65,536
constexpr size_t WS_W2N   = 13236608;    // 32,768
constexpr size_t WS_ENEW  = 13269376;    // bf16 [640000*128] natural order
constexpr size_t WS_NEED_ENEW = WS_ENEW + (size_t)TOTE * D * 2;

__device__ __forceinline__ f32x4 mfma16(bf16x8 a, bf16x8 b, f32x4 c) {
    return __builtin_amdgcn_mfma_f32_16x16x32_bf16(a, b, c, 0, 0, 0);
}
__device__ __forceinline__ __bf16 tobf(float x) { return (__bf16)x; }
__device__ __forceinline__ bf16x8 cvt8(float4 a, float4 b) {
    bf16x8 r;
    r[0]=tobf(a.x); r[1]=tobf(a.y); r[2]=tobf(a.z); r[3]=tobf(a.w);
    r[4]=tobf(b.x); r[5]=tobf(b.y); r[6]=tobf(b.z); r[7]=tobf(b.w);
    return r;
}
__device__ __forceinline__ float silu(float x) {
    float t = __builtin_amdgcn_exp2f(x * -1.44269504f);
    return x * __builtin_amdgcn_rcpf(1.0f + t);
}
__device__ __forceinline__ float bflo(uint v) { return __builtin_bit_cast(float, v << 16); }
__device__ __forceinline__ float bfhi(uint v) { return __builtin_bit_cast(float, v & 0xffff0000u); }

// ---- pack weights fp32 [K][128] -> bf16 fragment layout [kb][ct][lane][8] ----
__global__ void gnn_pack_kernel(const float* __restrict__ fe_w1, const float* __restrict__ fe_w2,
                                const float* __restrict__ fn_w1, const float* __restrict__ fn_w2,
                                ushort* __restrict__ w1e, ushort* __restrict__ w2e,
                                ushort* __restrict__ w1n, ushort* __restrict__ w2n) {
    int t = blockIdx.x * blockDim.x + threadIdx.x;
    const float* src; ushort* dst; int lt;
    if      (t <  6144) { src = fe_w1; dst = w1e; lt = t;         }
    else if (t <  8192) { src = fe_w2; dst = w2e; lt = t - 6144;  }
    else if (t < 12288) { src = fn_w1; dst = w1n; lt = t - 8192;  }
    else if (t < 14336) { src = fn_w2; dst = w2n; lt = t - 12288; }
    else return;
    int lane = lt & 63, ct = (lt >> 6) & 7, kb = lt >> 9;
    int n  = ct * 16 + (lane & 15);
    int k0 = kb * 32 + (lane >> 4) * 8;
    ushort tmp[8];
#pragma unroll
    for (int j = 0; j < 8; j++)
        tmp[j] = __builtin_bit_cast(ushort, tobf(src[(size_t)(k0 + j) * 128 + n]));
    uint4 pk;
    pk.x = tmp[0] | ((uint)tmp[1] << 16); pk.y = tmp[2] | ((uint)tmp[3] << 16);
    pk.z = tmp[4] | ((uint)tmp[5] << 16); pk.w = tmp[6] | ((uint)tmp[7] << 16);
    *(uint4*)(dst + (size_t)lt * 8) = pk;
}

__global__ void gnn_cnt_kernel(const int* __restrict__ edges, unsigned* __restrict__ cnt) {
    int t = blockIdx.x * blockDim.x + threadIdx.x;
    if (t >= TOTE) return;
    int er = edges[2 * t + 1];
    int b  = (t >= NEDGE) ? 1 : 0;
    int r  = min(max(er, 0), NNODE - 1);
    atomicAdd(&cnt[b * NNODE + r], 1u);
}

// ---- single-block exclusive scan over cnt[20000] -> off, cur ----
__global__ void gnn_scan_kernel(const unsigned* __restrict__ cnt,
                                unsigned* __restrict__ off, unsigned* __restrict__ cur) {
    __shared__ unsigned s[1024];
    const int t = threadIdx.x;
    const int CH = 20;
    unsigned loc[CH];
    unsigned sum = 0;
    int i0 = t * CH;
#pragma unroll
    for (int j = 0; j < CH; j++) {
        int i = i0 + j;
        unsigned v = (i < TOTN) ? cnt[i] : 0u;
        loc[j] = sum; sum += v;
    }
    s[t] = sum;
    __syncthreads();
    for (int d = 1; d < 1024; d <<= 1) {
        unsigned v = (t >= d) ? s[t - d] : 0u;
        __syncthreads();
        s[t] += v;
        __syncthreads();
    }
    unsigned base = (t > 0) ? s[t - 1] : 0u;
#pragma unroll
    for (int j = 0; j < CH; j++) {
        int i = i0 + j;
        if (i < TOTN) { off[i] = base + loc[j]; cur[i] = base + loc[j]; }
    }
}

// ---- scatter edge ids into CSR lists ----
__global__ void gnn_scatter_kernel(const int* __restrict__ edges,
                                   unsigned* __restrict__ cur, unsigned* __restrict__ elist) {
    int t = blockIdx.x * blockDim.x + threadIdx.x;
    if (t >= TOTE) return;
    int er = edges[2 * t + 1];
    int b  = (t >= NEDGE) ? 1 : 0;
    int r  = min(max(er, 0), NNODE - 1);
    unsigned pos = atomicAdd(&cur[b * NNODE + r], 1u);
    elist[pos] = (unsigned)t;
}

// ---- edge MLP, NATURAL order: all streams sequential except V gathers ----
__launch_bounds__(1024, 4)
__global__ void gnn_edge_kernel(const float* __restrict__ V, const float* __restrict__ E,
                                const int* __restrict__ edges,
                                const float* __restrict__ b1, const float* __restrict__ b2,
                                const float* __restrict__ g, const float* __restrict__ beta,
                                const ushort* __restrict__ w1p, const ushort* __restrict__ w2p,
                                ushort* __restrict__ enewp, float* __restrict__ E_out) {
    __shared__ __align__(16) ushort lds[81920];  // 96KB w1 pack + 16 x 4KB slabs = 160KB
    const int tid = threadIdx.x;
    const int wave = tid >> 6, lane = tid & 63;
    const int quad = lane >> 4, c16 = lane & 15;

    {   // stage w1 pack (6144 uint4)
        const uint4* s4 = (const uint4*)w1p;
        uint4* d4 = (uint4*)lds;
#pragma unroll
        for (int i = 0; i < 6; i++) d4[tid + i * 1024] = s4[tid + i * 1024];
    }
    __syncthreads();

    ushort* slab = lds + 49152 + wave * 2048;
    const int NT = TOTE / 256;  // 2500, exact

    for (int tile = blockIdx.x; tile < NT; tile += gridDim.x) {
        const int wp0 = tile * 256 + wave * 16;
        const int id = wp0 + c16;            // natural edge id, sequential
        const int bb = (id >= NEDGE) ? 1 : 0;
        const int2 e2 = ((const int2*)edges)[id];
        const int s = min(max(e2.x, 0), NNODE - 1), r = min(max(e2.y, 0), NNODE - 1);
        const float* pS = V + ((size_t)bb * NNODE + s) * D;
        const float* pR = V + ((size_t)bb * NNODE + r) * D;
        const float* pE = E + (size_t)id * D;
        const uint mask = (uint)(__ballot(e2.x >= 0 && e2.y >= 0) & 0xffffu);

        f32x4 acc[8];
        const f32x4 fz = {0.f, 0.f, 0.f, 0.f};
#pragma unroll
        for (int ct = 0; ct < 8; ct++) acc[ct] = fz;

        float ef[4][8];  // this lane's E-row chunk, kept f32 for the epilogue

        // GEMM1: [16 rows x 384] @ w1 -> [16 x 128]
#pragma unroll
        for (int kb = 0; kb < 12; kb++) {
            const float* base = (kb < 4) ? pS : (kb < 8) ? pR : pE;
            const int kloc = (kb & 3) * 32 + quad * 8;
            float4 x0 = *(const float4*)(base + kloc);
            float4 x1 = *(const float4*)(base + kloc + 4);
            if (kb >= 8) {
                ef[kb - 8][0] = x0.x; ef[kb - 8][1] = x0.y; ef[kb - 8][2] = x0.z; ef[kb - 8][3] = x0.w;
                ef[kb - 8][4] = x1.x; ef[kb - 8][5] = x1.y; ef[kb - 8][6] = x1.z; ef[kb - 8][7] = x1.w;
            }
            bf16x8 a = cvt8(x0, x1);
#pragma unroll
            for (int ct = 0; ct < 8; ct++) {
                bf16x8 bf = ((const bf16x8*)lds)[(kb * 8 + ct) * 64 + lane];
                acc[ct] = mfma16(a, bf, acc[ct]);
            }
        }

        // h = silu(acc + b1) -> wave-private slab (bf16, XOR-swizzled)
#pragma unroll
        for (int ct = 0; ct < 8; ct++) {
            float b1v = b1[ct * 16 + c16];
#pragma unroll
            for (int i = 0; i < 4; i++) {
                float h = silu(acc[ct][i] + b1v);
                int hrow = quad * 4 + i;
                int boff = hrow * 256 + ((2 * (ct * 16 + c16)) ^ (hrow << 4));
                slab[boff >> 1] = __builtin_bit_cast(ushort, tobf(h));
            }
        }

        f32x4 acc2[8];
#pragma unroll
        for (int ct = 0; ct < 8; ct++) acc2[ct] = fz;

        // GEMM2: [16 x 128] @ w2 -> [16 x 128]
#pragma unroll
        for (int kb2 = 0; kb2 < 4; kb2++) {
            int boff = c16 * 256 + ((kb2 * 64 + quad * 16) ^ (c16 << 4));
            bf16x8 a2 = *(const bf16x8*)((const char*)slab + boff);
#pragma unroll
            for (int ct = 0; ct < 8; ct++) {
                bf16x8 bf = *(const bf16x8*)(w2p + ((size_t)((kb2 * 8 + ct) * 64 + lane)) * 8);
                acc2[ct] = mfma16(a2, bf, acc2[ct]);
            }
        }

        // bias + LayerNorm
        float sm[4] = {0,0,0,0}, sq[4] = {0,0,0,0};
#pragma unroll
        for (int ct = 0; ct < 8; ct++) {
            float b2v = b2[ct * 16 + c16];
#pragma unroll
            for (int i = 0; i < 4; i++) {
                float y = acc2[ct][i] + b2v;
                acc2[ct][i] = y; sm[i] += y; sq[i] += y * y;
            }
        }
#pragma unroll
        for (int m = 1; m < 16; m <<= 1)
#pragma unroll
            for (int i = 0; i < 4; i++) {
                sm[i] += __shfl_xor(sm[i], m, 64);
                sq[i] += __shfl_xor(sq[i], m, 64);
            }
        float mu[4], rstd[4];
#pragma unroll
        for (int i = 0; i < 4; i++) {
            mu[i] = sm[i] * (1.0f / 128.0f);
            float var = sq[i] * (1.0f / 128.0f) - mu[i] * mu[i];
            rstd[i] = __builtin_amdgcn_rsqf(var + 1e-5f);
        }

        // masked e_new -> slab (bf16, swizzled)
#pragma unroll
        for (int ct = 0; ct < 8; ct++) {
            int cg = ct * 16 + c16;
            float gv = g[cg], bev = beta[cg];
#pragma unroll
            for (int i = 0; i < 4; i++) {
                float e = (acc2[ct][i] - mu[i]) * rstd[i] * gv + bev;
                int row = quad * 4 + i;
                e = ((mask >> row) & 1u) ? e : 0.0f;
                int boff = row * 256 + ((2 * cg) ^ (row << 4));
                slab[boff >> 1] = __builtin_bit_cast(ushort, tobf(e));
            }
        }

        // epilogue row-major: E from registers via shuffle; nt stores (sequential rows)
        const int rr = lane >> 2, seg = lane & 3;
        const int ide = wp0 + rr;
        const int srcl = seg * 16 + rr;  // lane holding E[rr], column chunk seg
#pragma unroll
        for (int j = 0; j < 4; j++) {
            int cb = (seg * 16 + j * 64) ^ (rr << 4);
            bf16x8 ev = *(const bf16x8*)((const char*)slab + rr * 256 + cb);
            size_t gb = (size_t)ide * D + seg * 8 + j * 32;
            f32x4 o0, o1;
            o0[0] = __shfl(ef[j][0], srcl) + (float)ev[0];
            o0[1] = __shfl(ef[j][1], srcl) + (float)ev[1];
            o0[2] = __shfl(ef[j][2], srcl) + (float)ev[2];
            o0[3] = __shfl(ef[j][3], srcl) + (float)ev[3];
            o1[0] = __shfl(ef[j][4], srcl) + (float)ev[4];
            o1[1] = __shfl(ef[j][5], srcl) + (float)ev[5];
            o1[2] = __shfl(ef[j][6], srcl) + (float)ev[6];
            o1[3] = __shfl(ef[j][7], srcl) + (float)ev[7];
            __builtin_nontemporal_store(o0, (f32x4*)(E_out + gb));
            __builtin_nontemporal_store(o1, (f32x4*)(E_out + gb + 4));
            if (enewp)
                __builtin_nontemporal_store(__builtin_bit_cast(u32x4, ev),
                                            (u32x4*)(enewp + gb));
        }
    }
}

// ---- aggregate: gather bf16 enew rows (natural order) via CSR elist ----
__launch_bounds__(256)
__global__ void gnn_agg_kernel(const float* __restrict__ E, const float* __restrict__ E_out,
                               const ushort* __restrict__ enewp,
                               const unsigned* __restrict__ off, const unsigned* __restrict__ cnt,
                               const unsigned* __restrict__ elist, float* __restrict__ agg) {
    const int lane = threadIdx.x & 63;
    const int wid = (blockIdx.x * blockDim.x + threadIdx.x) >> 6;
    const int nw = (gridDim.x * blockDim.x) >> 6;
    for (int n = wid; n < TOTN; n += nw) {
        unsigned base = off[n], c = cnt[n];
        float a0 = 0.f, a1 = 0.f;
        unsigned e = 0;
        if (enewp) {
            while (e + 8 <= c) {
                unsigned id[8]; uint v[8];
#pragma unroll
                for (int k = 0; k < 8; k++) id[k] = elist[base + e + k];
#pragma unroll
                for (int k = 0; k < 8; k++)
                    v[k] = __builtin_nontemporal_load(
                        (const uint*)(enewp + (size_t)id[k] * D) + lane);
#pragma unroll
                for (int k = 0; k < 8; k++) { a0 += bflo(v[k]); a1 += bfhi(v[k]); }
                e += 8;
            }
            for (; e < c; e++) {
                unsigned id = elist[base + e];
                uint v = __builtin_nontemporal_load((const uint*)(enewp + (size_t)id * D) + lane);
                a0 += bflo(v); a1 += bfhi(v);
            }
        } else {
            for (; e < c; e++) {
                unsigned id = elist[base + e];
                float2 eo = *(const float2*)(E_out + (size_t)id * D + lane * 2);
                float2 ee = *(const float2*)(E + (size_t)id * D + lane * 2);
                a0 += eo.x - ee.x; a1 += eo.y - ee.y;
            }
        }
        float rinv = 1.0f / (float)max(c, 1u);
        float2 outv; outv.x = a0 * rinv; outv.y = a1 * rinv;
        *(float2*)(agg + (size_t)n * D + lane * 2) = outv;
    }
}

// ---- node MLP: concat[V, agg] -> v_new; V_out = V + v_new ----
__launch_bounds__(768, 3)
__global__ void gnn_node_kernel(const float* __restrict__ V, const float* __restrict__ agg,
                                const float* __restrict__ b1, const float* __restrict__ b2,
                                const float* __restrict__ g, const float* __restrict__ beta,
                                const ushort* __restrict__ w1p, const ushort* __restrict__ w2p,
                                float* __restrict__ V_out) {
    __shared__ __align__(16) ushort lds[57344];  // 64KB w1n + 12 x 4KB slabs
    const int tid = threadIdx.x;
    const int wave = tid >> 6, lane = tid & 63;
    const int quad = lane >> 4, c16 = lane & 15;

    {
        const uint4* s4 = (const uint4*)w1p;
        uint4* d4 = (uint4*)lds;
#pragma unroll
        for (int i = 0; i < 6; i++) {
            int idx = tid + i * 768;
            if (idx < 4096) d4[idx] = s4[idx];
        }
    }
    __syncthreads();

    float b1v[8], b2v[8], gv[8], bev[8];
#pragma unroll
    for (int ct = 0; ct < 8; ct++) {
        int cg = ct * 16 + c16;
        b1v[ct] = b1[cg]; b2v[ct] = b2[cg]; gv[ct] = g[cg]; bev[ct] = beta[cg];
    }
    ushort* slab = lds + 32768 + wave * 2048;
    const int NT = (TOTN + 191) / 192;

    for (int tile = blockIdx.x; tile < NT; tile += gridDim.x) {
        const int wr0 = tile * 192 + wave * 16;
        const int gc = min(wr0 + c16, TOTN - 1);
        const float* pV = V   + (size_t)gc * D;
        const float* pG = agg + (size_t)gc * D;

        f32x4 acc[8];
        const f32x4 fz = {0.f, 0.f, 0.f, 0.f};
#pragma unroll
        for (int ct = 0; ct < 8; ct++) acc[ct] = fz;

#pragma unroll
        for (int kb = 0; kb < 8; kb++) {
            const float* base = (kb < 4) ? pV : pG;
            const int kloc = (kb & 3) * 32 + quad * 8;
            float4 x0 = *(const float4*)(base + kloc);
            float4 x1 = *(const float4*)(base + kloc + 4);
            bf16x8 a = cvt8(x0, x1);
#pragma unroll
            for (int ct = 0; ct < 8; ct++) {
                bf16x8 bf = ((const bf16x8*)lds)[(kb * 8 + ct) * 64 + lane];
                acc[ct] = mfma16(a, bf, acc[ct]);
            }
        }

#pragma unroll
        for (int ct = 0; ct < 8; ct++)
#pragma unroll
            for (int i = 0; i < 4; i++) {
                float h = silu(acc[ct][i] + b1v[ct]);
                int hrow = quad * 4 + i;
                int boff = hrow * 256 + ((2 * (ct * 16 + c16)) ^ (hrow << 4));
                slab[boff >> 1] = __builtin_bit_cast(ushort, tobf(h));
            }

        f32x4 acc2[8];
#pragma unroll
        for (int ct = 0; ct < 8; ct++) acc2[ct] = fz;
#pragma unroll
        for (int kb2 = 0; kb2 < 4; kb2++) {
            int boff = c16 * 256 + ((kb2 * 64 + quad * 16) ^ (c16 << 4));
            bf16x8 a2 = *(const bf16x8*)((const char*)slab + boff);
#pragma unroll
            for (int ct = 0; ct < 8; ct++) {
                bf16x8 bf = *(const bf16x8*)(w2p + ((size_t)((kb2 * 8 + ct) * 64 + lane)) * 8);
                acc2[ct] = mfma16(a2, bf, acc2[ct]);
            }
        }

        float sm[4] = {0,0,0,0}, sq[4] = {0,0,0,0};
#pragma unroll
        for (int ct = 0; ct < 8; ct++)
#pragma unroll
            for (int i = 0; i < 4; i++) {
                float y = acc2[ct][i] + b2v[ct];
                acc2[ct][i] = y; sm[i] += y; sq[i] += y * y;
            }
#pragma unroll
        for (int m = 1; m < 16; m <<= 1)
#pragma unroll
            for (int i = 0; i < 4; i++) {
                sm[i] += __shfl_xor(sm[i], m, 64);
                sq[i] += __shfl_xor(sq[i], m, 64);
            }
        float mu[4], rstd[4];
#pragma unroll
        for (int i = 0; i < 4; i++) {
            mu[i] = sm[i] * (1.0f / 128.0f);
            float var = sq[i] * (1.0f / 128.0f) - mu[i] * mu[i];
            rstd[i] = __builtin_amdgcn_rsqf(var + 1e-5f);
        }
#pragma unroll
        for (int ct = 0; ct < 8; ct++) {
            int cg = ct * 16 + c16;
#pragma unroll
            for (int i = 0; i < 4; i++) {
                int geo = wr0 + quad * 4 + i;
                if (geo < TOTN) {
                    float vn = (acc2[ct][i] - mu[i]) * rstd[i] * gv[ct] + bev[ct];
                    V_out[(size_t)geo * D + cg] = V[(size_t)geo * D + cg] + vn;
                }
            }
        }
    }
}

extern "C" void kernel_launch(void* const* d_in, const int* in_sizes, int n_in,
                              void* d_out, int out_size, void* d_ws, size_t ws_size,
                              hipStream_t stream) {
    const float* V     = (const float*)d_in[0];
    const float* E     = (const float*)d_in[1];
    const int*   edges = (const int*)d_in[2];
    const float* fe_w1 = (const float*)d_in[3];
    const float* fe_b1 = (const float*)d_in[4];
    const float* fe_w2 = (const float*)d_in[5];
    const float* fe_b2 = (const float*)d_in[6];
    const float* fe_g  = (const float*)d_in[7];
    const float* fe_be = (const float*)d_in[8];
    const float* fn_w1 = (const float*)d_in[9];
    const float* fn_b1 = (const float*)d_in[10];
    const float* fn_w2 = (const float*)d_in[11];
    const float* fn_b2 = (const float*)d_in[12];
    const float* fn_g  = (const float*)d_in[13];
    const float* fn_be = (const float*)d_in[14];

    char* ws = (char*)d_ws;
    unsigned* cnt   = (unsigned*)(ws + WS_CNT);
    unsigned* off   = (unsigned*)(ws + WS_OFF);
    unsigned* cur   = (unsigned*)(ws + WS_CUR);
    unsigned* elist = (unsigned*)(ws + WS_ELIST);
    float*    agg   = (float*)(ws + WS_AGG);
    ushort*   w1e   = (ushort*)(ws + WS_W1E);
    ushort*   w2e   = (ushort*)(ws + WS_W2E);
    ushort*   w1n   = (ushort*)(ws + WS_W1N);
    ushort*   w2n   = (ushort*)(ws + WS_W2N);
    ushort*   enewp = (ws_size >= WS_NEED_ENEW) ? (ushort*)(ws + WS_ENEW) : (ushort*)nullptr;

    float* V_out = (float*)d_out;
    float* E_out = V_out + (size_t)TOTN * D;

    (void)hipMemsetAsync(cnt, 0, TOTN * sizeof(unsigned), stream);
    gnn_pack_kernel<<<28, 512, 0, stream>>>(fe_w1, fe_w2, fn_w1, fn_w2, w1e, w2e, w1n, w2n);
    gnn_cnt_kernel<<<TOTE / 512, 512, 0, stream>>>(edges, cnt);
    gnn_scan_kernel<<<1, 1024, 0, stream>>>(cnt, off, cur);
    gnn_scatter_kernel<<<TOTE / 512, 512, 0, stream>>>(edges, cur, elist);
    gnn_edge_kernel<<<256, 1024, 0, stream>>>(V, E, edges, fe_b1, fe_b2, fe_g, fe_be,
                                              w1e, w2e, enewp, E_out);
    gnn_agg_kernel<<<1024, 256, 0, stream>>>(E, E_out, enewp, off, cnt, elist, agg);
    gnn_node_kernel<<<105, 768, 0, stream>>>(V, agg, fn_b1, fn_b2, fn_g, fn_be,
                                             w1n, w2n, V_out);
}

// Round 7
// 1266.362 us; speedup vs baseline: 1.0847x; 1.0847x over previous
//
#include <hip/hip_runtime.h>

typedef float f32x4 __attribute__((ext_vector_type(4)));
typedef __bf16 bf16x8 __attribute__((ext_vector_type(8)));

constexpr int BATCH = 2;
constexpr int NNODE = 10000;
constexpr int NEDGE = 320000;
constexpr int D = 128;
constexpr int TOTN = BATCH * NNODE;    // 20000
constexpr int TOTE = BATCH * NEDGE;    // 640000

// ---- workspace layout (bytes) ----
constexpr size_t WS_CNT   = 0;           // u32 [20000]
constexpr size_t WS_OFF   = 80000;       // u32 [20000]
constexpr size_t WS_CUR   = 160000;      // u32 [20000]
constexpr size_t WS_ELIST = 240000;      // u32 [640000]
constexpr size_t WS_AGG   = 2800000;     // f32 [20000*128]
constexpr size_t WS_W1E   = 13040000;    // bf16 pack 98,304
constexpr size_t WS_W2E   = 13138304;    // 32,768
constexpr size_t WS_W1N   = 13171072;    // 65,536
constexpr size_t WS_W2N   = 13236608;    // 32,768
constexpr size_t WS_ENEW  = 13269376;    // bf16 [640000*128] CSR order
constexpr size_t WS_NEED_ENEW = WS_ENEW + (size_t)TOTE * D * 2;

__device__ __forceinline__ f32x4 mfma16(bf16x8 a, bf16x8 b, f32x4 c) {
    return __builtin_amdgcn_mfma_f32_16x16x32_bf16(a, b, c, 0, 0, 0);
}
__device__ __forceinline__ __bf16 tobf(float x) { return (__bf16)x; }
__device__ __forceinline__ bf16x8 cvt8(float4 a, float4 b) {
    bf16x8 r;
    r[0]=tobf(a.x); r[1]=tobf(a.y); r[2]=tobf(a.z); r[3]=tobf(a.w);
    r[4]=tobf(b.x); r[5]=tobf(b.y); r[6]=tobf(b.z); r[7]=tobf(b.w);
    return r;
}
__device__ __forceinline__ float silu(float x) {
    float t = __builtin_amdgcn_exp2f(x * -1.44269504f);
    return x * __builtin_amdgcn_rcpf(1.0f + t);
}
__device__ __forceinline__ float bflo(uint v) { return __builtin_bit_cast(float, v << 16); }
__device__ __forceinline__ float bfhi(uint v) { return __builtin_bit_cast(float, v & 0xffff0000u); }

// ---- pack weights fp32 [K][128] -> bf16 fragment layout [kb][ct][lane][8] ----
__global__ void gnn_pack_kernel(const float* __restrict__ fe_w1, const float* __restrict__ fe_w2,
                                const float* __restrict__ fn_w1, const float* __restrict__ fn_w2,
                                ushort* __restrict__ w1e, ushort* __restrict__ w2e,
                                ushort* __restrict__ w1n, ushort* __restrict__ w2n) {
    int t = blockIdx.x * blockDim.x + threadIdx.x;
    const float* src; ushort* dst; int lt;
    if      (t <  6144) { src = fe_w1; dst = w1e; lt = t;         }
    else if (t <  8192) { src = fe_w2; dst = w2e; lt = t - 6144;  }
    else if (t < 12288) { src = fn_w1; dst = w1n; lt = t - 8192;  }
    else if (t < 14336) { src = fn_w2; dst = w2n; lt = t - 12288; }
    else return;
    int lane = lt & 63, ct = (lt >> 6) & 7, kb = lt >> 9;
    int n  = ct * 16 + (lane & 15);
    int k0 = kb * 32 + (lane >> 4) * 8;
    ushort tmp[8];
#pragma unroll
    for (int j = 0; j < 8; j++)
        tmp[j] = __builtin_bit_cast(ushort, tobf(src[(size_t)(k0 + j) * 128 + n]));
    uint4 pk;
    pk.x = tmp[0] | ((uint)tmp[1] << 16); pk.y = tmp[2] | ((uint)tmp[3] << 16);
    pk.z = tmp[4] | ((uint)tmp[5] << 16); pk.w = tmp[6] | ((uint)tmp[7] << 16);
    *(uint4*)(dst + (size_t)lt * 8) = pk;
}

__global__ void gnn_cnt_kernel(const int* __restrict__ edges, unsigned* __restrict__ cnt) {
    int t = blockIdx.x * blockDim.x + threadIdx.x;
    if (t >= TOTE) return;
    int er = edges[2 * t + 1];
    int b  = (t >= NEDGE) ? 1 : 0;
    int r  = min(max(er, 0), NNODE - 1);
    atomicAdd(&cnt[b * NNODE + r], 1u);
}

// ---- single-block exclusive scan over cnt[20000] -> off, cur ----
__global__ void gnn_scan_kernel(const unsigned* __restrict__ cnt,
                                unsigned* __restrict__ off, unsigned* __restrict__ cur) {
    __shared__ unsigned s[1024];
    const int t = threadIdx.x;
    const int CH = 20;
    unsigned loc[CH];
    unsigned sum = 0;
    int i0 = t * CH;
#pragma unroll
    for (int j = 0; j < CH; j++) {
        int i = i0 + j;
        unsigned v = (i < TOTN) ? cnt[i] : 0u;
        loc[j] = sum; sum += v;
    }
    s[t] = sum;
    __syncthreads();
    for (int d = 1; d < 1024; d <<= 1) {
        unsigned v = (t >= d) ? s[t - d] : 0u;
        __syncthreads();
        s[t] += v;
        __syncthreads();
    }
    unsigned base = (t > 0) ? s[t - 1] : 0u;
#pragma unroll
    for (int j = 0; j < CH; j++) {
        int i = i0 + j;
        if (i < TOTN) { off[i] = base + loc[j]; cur[i] = base + loc[j]; }
    }
}

// ---- scatter edge ids into CSR lists ----
__global__ void gnn_scatter_kernel(const int* __restrict__ edges,
                                   unsigned* __restrict__ cur, unsigned* __restrict__ elist) {
    int t = blockIdx.x * blockDim.x + threadIdx.x;
    if (t >= TOTE) return;
    int er = edges[2 * t + 1];
    int b  = (t >= NEDGE) ? 1 : 0;
    int r  = min(max(er, 0), NNODE - 1);
    unsigned pos = atomicAdd(&cur[b * NNODE + r], 1u);
    elist[pos] = (unsigned)t;
}

// ---- edge MLP over CSR-ordered edges; E_out fused; enew (bf16) at CSR position ----
__launch_bounds__(1024)
__global__ void gnn_edge_kernel(const float* __restrict__ V, const float* __restrict__ E,
                                const int* __restrict__ edges, const unsigned* __restrict__ elist,
                                const float* __restrict__ b1, const float* __restrict__ b2,
                                const float* __restrict__ g, const float* __restrict__ beta,
                                const ushort* __restrict__ w1p, const ushort* __restrict__ w2p,
                                ushort* __restrict__ enewp, float* __restrict__ E_out) {
    __shared__ __align__(16) ushort lds[81920];  // 96KB w1 pack + 16 x 4KB slabs = 160KB
    const int tid = threadIdx.x;
    const int wave = tid >> 6, lane = tid & 63;
    const int quad = lane >> 4, c16 = lane & 15;

    {   // stage w1 pack (6144 uint4)
        const uint4* s4 = (const uint4*)w1p;
        uint4* d4 = (uint4*)lds;
#pragma unroll
        for (int i = 0; i < 6; i++) d4[tid + i * 1024] = s4[tid + i * 1024];
    }
    __syncthreads();

    ushort* slab = lds + 49152 + wave * 2048;
    const int NT = TOTE / 256;  // 2500, exact

    for (int tile = blockIdx.x; tile < NT; tile += gridDim.x) {
        const int wp0 = tile * 256 + wave * 16;
        const int p = wp0 + c16;
        const int id = (int)elist[p];
        const int bb = (id >= NEDGE) ? 1 : 0;
        const int es = edges[2 * id], er = edges[2 * id + 1];
        const int s = min(max(es, 0), NNODE - 1), r = min(max(er, 0), NNODE - 1);
        const float* pS = V + ((size_t)bb * NNODE + s) * D;
        const float* pR = V + ((size_t)bb * NNODE + r) * D;
        const float* pE = E + (size_t)id * D;
        const uint mask = (uint)(__ballot(es >= 0 && er >= 0) & 0xffffu);

        // issue ALL 24 A-loads up front -> max memory-level parallelism
        float4 xa[24];
#pragma unroll
        for (int kb = 0; kb < 12; kb++) {
            const float* base = (kb < 4) ? pS : (kb < 8) ? pR : pE;
            const float* ptr = base + (kb & 3) * 32 + quad * 8;
            xa[2 * kb]     = *(const float4*)ptr;
            xa[2 * kb + 1] = *(const float4*)(ptr + 4);
        }

        f32x4 acc[8];
        const f32x4 fz = {0.f, 0.f, 0.f, 0.f};
#pragma unroll
        for (int ct = 0; ct < 8; ct++) acc[ct] = fz;

        // GEMM1: [16 rows x 384] @ w1 -> [16 x 128]
#pragma unroll
        for (int kb = 0; kb < 12; kb++) {
            bf16x8 a = cvt8(xa[2 * kb], xa[2 * kb + 1]);
#pragma unroll
            for (int ct = 0; ct < 8; ct++) {
                bf16x8 bf = ((const bf16x8*)lds)[(kb * 8 + ct) * 64 + lane];
                acc[ct] = mfma16(a, bf, acc[ct]);
            }
        }

        // h = silu(acc + b1) -> wave-private slab (bf16, XOR-swizzled)
#pragma unroll
        for (int ct = 0; ct < 8; ct++) {
            float b1v = b1[ct * 16 + c16];
#pragma unroll
            for (int i = 0; i < 4; i++) {
                float h = silu(acc[ct][i] + b1v);
                int hrow = quad * 4 + i;
                int boff = hrow * 256 + ((2 * (ct * 16 + c16)) ^ (hrow << 4));
                slab[boff >> 1] = __builtin_bit_cast(ushort, tobf(h));
            }
        }

        f32x4 acc2[8];
#pragma unroll
        for (int ct = 0; ct < 8; ct++) acc2[ct] = fz;

        // GEMM2: [16 x 128] @ w2 -> [16 x 128]
#pragma unroll
        for (int kb2 = 0; kb2 < 4; kb2++) {
            int boff = c16 * 256 + ((kb2 * 64 + quad * 16) ^ (c16 << 4));
            bf16x8 a2 = *(const bf16x8*)((const char*)slab + boff);
#pragma unroll
            for (int ct = 0; ct < 8; ct++) {
                bf16x8 bf = *(const bf16x8*)(w2p + ((size_t)((kb2 * 8 + ct) * 64 + lane)) * 8);
                acc2[ct] = mfma16(a2, bf, acc2[ct]);
            }
        }

        // bias + LayerNorm
        float sm[4] = {0,0,0,0}, sq[4] = {0,0,0,0};
#pragma unroll
        for (int ct = 0; ct < 8; ct++) {
            float b2v = b2[ct * 16 + c16];
#pragma unroll
            for (int i = 0; i < 4; i++) {
                float y = acc2[ct][i] + b2v;
                acc2[ct][i] = y; sm[i] += y; sq[i] += y * y;
            }
        }
#pragma unroll
        for (int m = 1; m < 16; m <<= 1)
#pragma unroll
            for (int i = 0; i < 4; i++) {
                sm[i] += __shfl_xor(sm[i], m, 64);
                sq[i] += __shfl_xor(sq[i], m, 64);
            }
        float mu[4], rstd[4];
#pragma unroll
        for (int i = 0; i < 4; i++) {
            mu[i] = sm[i] * (1.0f / 128.0f);
            float var = sq[i] * (1.0f / 128.0f) - mu[i] * mu[i];
            rstd[i] = __builtin_amdgcn_rsqf(var + 1e-5f);
        }

        // masked e_new -> slab (bf16, swizzled)
#pragma unroll
        for (int ct = 0; ct < 8; ct++) {
            int cg = ct * 16 + c16;
            float gv = g[cg], bev = beta[cg];
#pragma unroll
            for (int i = 0; i < 4; i++) {
                float e = (acc2[ct][i] - mu[i]) * rstd[i] * gv + bev;
                int row = quad * 4 + i;
                e = ((mask >> row) & 1u) ? e : 0.0f;
                int boff = row * 256 + ((2 * cg) ^ (row << 4));
                slab[boff >> 1] = __builtin_bit_cast(ushort, tobf(e));
            }
        }

        // epilogue: E re-read (L2-hot), E_out = E + e_new (scattered), enew @ CSR pos
        const int rr = lane >> 2, seg = lane & 3;
        const int ps = wp0 + rr;
        const int idr = (int)elist[ps];
#pragma unroll
        for (int j = 0; j < 4; j++) {
            int cb = (seg * 16 + j * 64) ^ (rr << 4);
            bf16x8 ev = *(const bf16x8*)((const char*)slab + rr * 256 + cb);
            size_t gb = (size_t)idr * D + seg * 8 + j * 32;
            float4 e0 = *(const float4*)(E + gb);
            float4 e1 = *(const float4*)(E + gb + 4);
            float4 o0, o1;
            o0.x = e0.x + (float)ev[0]; o0.y = e0.y + (float)ev[1];
            o0.z = e0.z + (float)ev[2]; o0.w = e0.w + (float)ev[3];
            o1.x = e1.x + (float)ev[4]; o1.y = e1.y + (float)ev[5];
            o1.z = e1.z + (float)ev[6]; o1.w = e1.w + (float)ev[7];
            *(float4*)(E_out + gb) = o0;
            *(float4*)(E_out + gb + 4) = o1;
            if (enewp)
                *(bf16x8*)(enewp + (size_t)ps * D + seg * 8 + j * 32) = ev;
        }
    }
}

// ---- aggregate: CSR-sequential mean of enew rows per node ----
__global__ void gnn_agg_kernel(const float* __restrict__ E, const float* __restrict__ E_out,
                               const ushort* __restrict__ enewp,
                               const unsigned* __restrict__ off, const unsigned* __restrict__ cnt,
                               const unsigned* __restrict__ elist, float* __restrict__ agg) {
    const int lane = threadIdx.x & 63;
    const int wid = (blockIdx.x * blockDim.x + threadIdx.x) >> 6;
    const int nw = (gridDim.x * blockDim.x) >> 6;
    for (int n = wid; n < TOTN; n += nw) {
        unsigned base = off[n], c = cnt[n];
        float a0 = 0.f, a1 = 0.f;
        unsigned e = 0;
        if (enewp) {
            const uint* rowp = (const uint*)(enewp + (size_t)base * D) + lane;
            while (e + 4 <= c) {
                uint v0 = rowp[0], v1 = rowp[64], v2 = rowp[128], v3 = rowp[192];
                a0 += bflo(v0) + bflo(v1) + bflo(v2) + bflo(v3);
                a1 += bfhi(v0) + bfhi(v1) + bfhi(v2) + bfhi(v3);
                rowp += 256; e += 4;
            }
            for (; e < c; e++) { uint v = *rowp; a0 += bflo(v); a1 += bfhi(v); rowp += 64; }
        } else {
            for (; e < c; e++) {
                unsigned id = elist[base + e];
                float2 eo = *(const float2*)(E_out + (size_t)id * D + lane * 2);
                float2 ee = *(const float2*)(E + (size_t)id * D + lane * 2);
                a0 += eo.x - ee.x; a1 += eo.y - ee.y;
            }
        }
        float rinv = 1.0f / (float)max(c, 1u);
        float2 outv; outv.x = a0 * rinv; outv.y = a1 * rinv;
        *(float2*)(agg + (size_t)n * D + lane * 2) = outv;
    }
}

// ---- node MLP: concat[V, agg] -> v_new; V_out = V + v_new ----
__launch_bounds__(1024)
__global__ void gnn_node_kernel(const float* __restrict__ V, const float* __restrict__ agg,
                                const float* __restrict__ b1, const float* __restrict__ b2,
                                const float* __restrict__ g, const float* __restrict__ beta,
                                const ushort* __restrict__ w1p, const ushort* __restrict__ w2p,
                                float* __restrict__ V_out) {
    __shared__ __align__(16) ushort lds[65536];  // 64KB w1n + 16 x 4KB slabs = 128KB
    const int tid = threadIdx.x;
    const int wave = tid >> 6, lane = tid & 63;
    const int quad = lane >> 4, c16 = lane & 15;

    {   // stage w1n pack (4096 uint4)
        const uint4* s4 = (const uint4*)w1p;
        uint4* d4 = (uint4*)lds;
#pragma unroll
        for (int i = 0; i < 4; i++) d4[tid + i * 1024] = s4[tid + i * 1024];
    }
    __syncthreads();

    ushort* slab = lds + 32768 + wave * 2048;
    const int NT = (TOTN + 255) / 256;  // 79

    for (int tile = blockIdx.x; tile < NT; tile += gridDim.x) {
        const int wr0 = tile * 256 + wave * 16;
        const int gc = min(wr0 + c16, TOTN - 1);
        const float* pV = V   + (size_t)gc * D;
        const float* pG = agg + (size_t)gc * D;

        float4 xa[16];
#pragma unroll
        for (int kb = 0; kb < 8; kb++) {
            const float* base = (kb < 4) ? pV : pG;
            const float* ptr = base + (kb & 3) * 32 + quad * 8;
            xa[2 * kb]     = *(const float4*)ptr;
            xa[2 * kb + 1] = *(const float4*)(ptr + 4);
        }

        f32x4 acc[8];
        const f32x4 fz = {0.f, 0.f, 0.f, 0.f};
#pragma unroll
        for (int ct = 0; ct < 8; ct++) acc[ct] = fz;

#pragma unroll
        for (int kb = 0; kb < 8; kb++) {
            bf16x8 a = cvt8(xa[2 * kb], xa[2 * kb + 1]);
#pragma unroll
            for (int ct = 0; ct < 8; ct++) {
                bf16x8 bf = ((const bf16x8*)lds)[(kb * 8 + ct) * 64 + lane];
                acc[ct] = mfma16(a, bf, acc[ct]);
            }
        }

#pragma unroll
        for (int ct = 0; ct < 8; ct++) {
            float b1v = b1[ct * 16 + c16];
#pragma unroll
            for (int i = 0; i < 4; i++) {
                float h = silu(acc[ct][i] + b1v);
                int hrow = quad * 4 + i;
                int boff = hrow * 256 + ((2 * (ct * 16 + c16)) ^ (hrow << 4));
                slab[boff >> 1] = __builtin_bit_cast(ushort, tobf(h));
            }
        }

        f32x4 acc2[8];
#pragma unroll
        for (int ct = 0; ct < 8; ct++) acc2[ct] = fz;
#pragma unroll
        for (int kb2 = 0; kb2 < 4; kb2++) {
            int boff = c16 * 256 + ((kb2 * 64 + quad * 16) ^ (c16 << 4));
            bf16x8 a2 = *(const bf16x8*)((const char*)slab + boff);
#pragma unroll
            for (int ct = 0; ct < 8; ct++) {
                bf16x8 bf = *(const bf16x8*)(w2p + ((size_t)((kb2 * 8 + ct) * 64 + lane)) * 8);
                acc2[ct] = mfma16(a2, bf, acc2[ct]);
            }
        }

        float sm[4] = {0,0,0,0}, sq[4] = {0,0,0,0};
#pragma unroll
        for (int ct = 0; ct < 8; ct++) {
            float b2v = b2[ct * 16 + c16];
#pragma unroll
            for (int i = 0; i < 4; i++) {
                float y = acc2[ct][i] + b2v;
                acc2[ct][i] = y; sm[i] += y; sq[i] += y * y;
            }
        }
#pragma unroll
        for (int m = 1; m < 16; m <<= 1)
#pragma unroll
            for (int i = 0; i < 4; i++) {
                sm[i] += __shfl_xor(sm[i], m, 64);
                sq[i] += __shfl_xor(sq[i], m, 64);
            }
        float mu[4], rstd[4];
#pragma unroll
        for (int i = 0; i < 4; i++) {
            mu[i] = sm[i] * (1.0f / 128.0f);
            float var = sq[i] * (1.0f / 128.0f) - mu[i] * mu[i];
            rstd[i] = __builtin_amdgcn_rsqf(var + 1e-5f);
        }
#pragma unroll
        for (int ct = 0; ct < 8; ct++) {
            int cg = ct * 16 + c16;
            float gv = g[cg], bev = beta[cg];
#pragma unroll
            for (int i = 0; i < 4; i++) {
                int geo = wr0 + quad * 4 + i;
                if (geo < TOTN) {
                    float vn = (acc2[ct][i] - mu[i]) * rstd[i] * gv + bev;
                    V_out[(size_t)geo * D + cg] = V[(size_t)geo * D + cg] + vn;
                }
            }
        }
    }
}

extern "C" void kernel_launch(void* const* d_in, const int* in_sizes, int n_in,
                              void* d_out, int out_size, void* d_ws, size_t ws_size,
                              hipStream_t stream) {
    const float* V     = (const float*)d_in[0];
    const float* E     = (const float*)d_in[1];
    const int*   edges = (const int*)d_in[2];
    const float* fe_w1 = (const float*)d_in[3];
    const float* fe_b1 = (const float*)d_in[4];
    const float* fe_w2 = (const float*)d_in[5];
    const float* fe_b2 = (const float*)d_in[6];
    const float* fe_g  = (const float*)d_in[7];
    const float* fe_be = (const float*)d_in[8];
    const float* fn_w1 = (const float*)d_in[9];
    const float* fn_b1 = (const float*)d_in[10];
    const float* fn_w2 = (const float*)d_in[11];
    const float* fn_b2 = (const float*)d_in[12];
    const float* fn_g  = (const float*)d_in[13];
    const float* fn_be = (const float*)d_in[14];

    char* ws = (char*)d_ws;
    unsigned* cnt   = (unsigned*)(ws + WS_CNT);
    unsigned* off   = (unsigned*)(ws + WS_OFF);
    unsigned* cur   = (unsigned*)(ws + WS_CUR);
    unsigned* elist = (unsigned*)(ws + WS_ELIST);
    float*    agg   = (float*)(ws + WS_AGG);
    ushort*   w1e   = (ushort*)(ws + WS_W1E);
    ushort*   w2e   = (ushort*)(ws + WS_W2E);
    ushort*   w1n   = (ushort*)(ws + WS_W1N);
    ushort*   w2n   = (ushort*)(ws + WS_W2N);
    ushort*   enewp = (ws_size >= WS_NEED_ENEW) ? (ushort*)(ws + WS_ENEW) : (ushort*)nullptr;

    float* V_out = (float*)d_out;
    float* E_out = V_out + (size_t)TOTN * D;

    (void)hipMemsetAsync(cnt, 0, TOTN * sizeof(unsigned), stream);
    gnn_pack_kernel<<<28, 512, 0, stream>>>(fe_w1, fe_w2, fn_w1, fn_w2, w1e, w2e, w1n, w2n);
    gnn_cnt_kernel<<<TOTE / 512, 512, 0, stream>>>(edges, cnt);
    gnn_scan_kernel<<<1, 1024, 0, stream>>>(cnt, off, cur);
    gnn_scatter_kernel<<<TOTE / 512, 512, 0, stream>>>(edges, cur, elist);
    gnn_edge_kernel<<<256, 1024, 0, stream>>>(V, E, edges, elist, fe_b1, fe_b2, fe_g, fe_be,
                                              w1e, w2e, enewp, E_out);
    gnn_agg_kernel<<<1024, 256, 0, stream>>>(E, E_out, enewp, off, cnt, elist, agg);
    gnn_node_kernel<<<79, 1024, 0, stream>>>(V, agg, fn_b1, fn_b2, fn_g, fn_be,
                                             w1n, w2n, V_out);
}

// Round 8
// 1122.268 us; speedup vs baseline: 1.2239x; 1.1284x over previous
//
#include <hip/hip_runtime.h>

typedef float f32x4 __attribute__((ext_vector_type(4)));
typedef __bf16 bf16x8 __attribute__((ext_vector_type(8)));

constexpr int BATCH = 2;
constexpr int NNODE = 10000;
constexpr int NEDGE = 320000;
constexpr int D = 128;
constexpr int TOTN = BATCH * NNODE;    // 20000
constexpr int TOTE = BATCH * NEDGE;    // 640000

// ---- workspace layout (bytes) ----
constexpr size_t WS_CNT   = 0;           // u32 [20000]
constexpr size_t WS_OFF   = 80000;       // u32 [20000]
constexpr size_t WS_CUR   = 160000;      // u32 [20000]
constexpr size_t WS_ELIST = 240000;      // u32 [640000]
constexpr size_t WS_AGG   = 2800000;     // f32 [20000*128]
constexpr size_t WS_W1E   = 13040000;    // bf16 pack 98,304
constexpr size_t WS_W2E   = 13138304;    // 32,768
constexpr size_t WS_W1N   = 13171072;    // 65,536
constexpr size_t WS_W2N   = 13236608;    // 32,768
constexpr size_t WS_ENEW  = 13269376;    // bf16 [640000*128] CSR order
constexpr size_t WS_NEED_ENEW = WS_ENEW + (size_t)TOTE * D * 2;

__device__ __forceinline__ f32x4 mfma16(bf16x8 a, bf16x8 b, f32x4 c) {
    return __builtin_amdgcn_mfma_f32_16x16x32_bf16(a, b, c, 0, 0, 0);
}
__device__ __forceinline__ __bf16 tobf(float x) { return (__bf16)x; }
__device__ __forceinline__ bf16x8 cvt8(float4 a, float4 b) {
    bf16x8 r;
    r[0]=tobf(a.x); r[1]=tobf(a.y); r[2]=tobf(a.z); r[3]=tobf(a.w);
    r[4]=tobf(b.x); r[5]=tobf(b.y); r[6]=tobf(b.z); r[7]=tobf(b.w);
    return r;
}
__device__ __forceinline__ float silu(float x) {
    float t = __builtin_amdgcn_exp2f(x * -1.44269504f);
    return x * __builtin_amdgcn_rcpf(1.0f + t);
}
__device__ __forceinline__ float bflo(uint v) { return __builtin_bit_cast(float, v << 16); }
__device__ __forceinline__ float bfhi(uint v) { return __builtin_bit_cast(float, v & 0xffff0000u); }

// ---- pack weights fp32 [K][128] -> bf16 fragment layout [kb][ct][lane][8] ----
__global__ void gnn_pack_kernel(const float* __restrict__ fe_w1, const float* __restrict__ fe_w2,
                                const float* __restrict__ fn_w1, const float* __restrict__ fn_w2,
                                ushort* __restrict__ w1e, ushort* __restrict__ w2e,
                                ushort* __restrict__ w1n, ushort* __restrict__ w2n) {
    int t = blockIdx.x * blockDim.x + threadIdx.x;
    const float* src; ushort* dst; int lt;
    if      (t <  6144) { src = fe_w1; dst = w1e; lt = t;         }
    else if (t <  8192) { src = fe_w2; dst = w2e; lt = t - 6144;  }
    else if (t < 12288) { src = fn_w1; dst = w1n; lt = t - 8192;  }
    else if (t < 14336) { src = fn_w2; dst = w2n; lt = t - 12288; }
    else return;
    int lane = lt & 63, ct = (lt >> 6) & 7, kb = lt >> 9;
    int n  = ct * 16 + (lane & 15);
    int k0 = kb * 32 + (lane >> 4) * 8;
    ushort tmp[8];
#pragma unroll
    for (int j = 0; j < 8; j++)
        tmp[j] = __builtin_bit_cast(ushort, tobf(src[(size_t)(k0 + j) * 128 + n]));
    uint4 pk;
    pk.x = tmp[0] | ((uint)tmp[1] << 16); pk.y = tmp[2] | ((uint)tmp[3] << 16);
    pk.z = tmp[4] | ((uint)tmp[5] << 16); pk.w = tmp[6] | ((uint)tmp[7] << 16);
    *(uint4*)(dst + (size_t)lt * 8) = pk;
}

// ---- per-receiver counts, LDS-privatized (8 blocks x 80KB LDS) ----
__global__ void gnn_cnt_kernel(const int* __restrict__ edges, unsigned* __restrict__ cnt) {
    __shared__ unsigned lc[TOTN];
    const int tid = threadIdx.x;
    for (int i = tid; i < TOTN; i += 1024) lc[i] = 0u;
    __syncthreads();
    const int chunk = TOTE / 8;  // 80000
    const int b0 = blockIdx.x * chunk;
    for (int i = b0 + tid; i < b0 + chunk; i += 1024) {
        int er = edges[2 * i + 1];
        int b  = (i >= NEDGE) ? 1 : 0;
        int r  = min(max(er, 0), NNODE - 1);
        atomicAdd(&lc[b * NNODE + r], 1u);
    }
    __syncthreads();
    for (int i = tid; i < TOTN; i += 1024) {
        unsigned v = lc[i];
        if (v) atomicAdd(&cnt[i], v);
    }
}

// ---- single-block exclusive scan over cnt[20000] -> off, cur ----
__global__ void gnn_scan_kernel(const unsigned* __restrict__ cnt,
                                unsigned* __restrict__ off, unsigned* __restrict__ cur) {
    __shared__ unsigned s[1024];
    const int t = threadIdx.x;
    const int CH = 20;
    unsigned loc[CH];
    unsigned sum = 0;
    int i0 = t * CH;
#pragma unroll
    for (int j = 0; j < CH; j++) {
        int i = i0 + j;
        unsigned v = (i < TOTN) ? cnt[i] : 0u;
        loc[j] = sum; sum += v;
    }
    s[t] = sum;
    __syncthreads();
    for (int d = 1; d < 1024; d <<= 1) {
        unsigned v = (t >= d) ? s[t - d] : 0u;
        __syncthreads();
        s[t] += v;
        __syncthreads();
    }
    unsigned base = (t > 0) ? s[t - 1] : 0u;
#pragma unroll
    for (int j = 0; j < CH; j++) {
        int i = i0 + j;
        if (i < TOTN) { off[i] = base + loc[j]; cur[i] = base + loc[j]; }
    }
}

// ---- scatter edge ids into CSR lists ----
__global__ void gnn_scatter_kernel(const int* __restrict__ edges,
                                   unsigned* __restrict__ cur, unsigned* __restrict__ elist) {
    int t = blockIdx.x * blockDim.x + threadIdx.x;
    if (t >= TOTE) return;
    int er = edges[2 * t + 1];
    int b  = (t >= NEDGE) ? 1 : 0;
    int r  = min(max(er, 0), NNODE - 1);
    unsigned pos = atomicAdd(&cur[b * NNODE + r], 1u);
    elist[pos] = (unsigned)t;
}

// ---- edge MLP over CSR-ordered edges; weights from L2; slab-only LDS ----
__launch_bounds__(512)
__global__ void gnn_edge_kernel(const float* __restrict__ V, const float* __restrict__ E,
                                const int* __restrict__ edges, const unsigned* __restrict__ elist,
                                const float* __restrict__ b1, const float* __restrict__ b2,
                                const float* __restrict__ g, const float* __restrict__ beta,
                                const ushort* __restrict__ w1p, const ushort* __restrict__ w2p,
                                ushort* __restrict__ enewp, float* __restrict__ E_out) {
    __shared__ __align__(16) ushort lds[16384];  // 8 waves x 4KB slabs = 32KB
    const int tid = threadIdx.x;
    const int wave = tid >> 6, lane = tid & 63;
    const int quad = lane >> 4, c16 = lane & 15;
    ushort* slab = lds + wave * 2048;

    const int wp0 = blockIdx.x * 256 + wave * 32;  // grid = TOTE/256 = 2500 blocks

    const float* pA[2][3]; uint mask16[2];
#pragma unroll
    for (int rt = 0; rt < 2; rt++) {
        int p  = wp0 + rt * 16 + c16;
        int id = (int)elist[p];
        int bb = (id >= NEDGE) ? 1 : 0;
        int es = edges[2 * id], er = edges[2 * id + 1];
        int s = min(max(es, 0), NNODE - 1), r = min(max(er, 0), NNODE - 1);
        pA[rt][0] = V + ((size_t)bb * NNODE + s) * D;
        pA[rt][1] = V + ((size_t)bb * NNODE + r) * D;
        pA[rt][2] = E + (size_t)id * D;
        mask16[rt] = (uint)(__ballot(es >= 0 && er >= 0) & 0xffffu);
    }

    f32x4 acc1[2][8];
    const f32x4 fz = {0.f, 0.f, 0.f, 0.f};
#pragma unroll
    for (int rt = 0; rt < 2; rt++)
#pragma unroll
        for (int ct = 0; ct < 8; ct++) acc1[rt][ct] = fz;

    // GEMM1: [32 rows x 384] @ w1 -> [32 x 128]; B-frags from L2 (shared across waves)
#pragma unroll
    for (int kb = 0; kb < 12; kb++) {
        const int part = kb >> 2;
        const int kloc = (kb & 3) * 32 + quad * 8;
        bf16x8 a[2];
#pragma unroll
        for (int rt = 0; rt < 2; rt++) {
            const float* p = pA[rt][part] + kloc;
            float4 x0 = *(const float4*)p;
            float4 x1 = *(const float4*)(p + 4);
            a[rt] = cvt8(x0, x1);
        }
#pragma unroll
        for (int ct = 0; ct < 8; ct++) {
            bf16x8 bf = *(const bf16x8*)(w1p + ((size_t)((kb * 8 + ct) * 64 + lane)) * 8);
            acc1[0][ct] = mfma16(a[0], bf, acc1[0][ct]);
            acc1[1][ct] = mfma16(a[1], bf, acc1[1][ct]);
        }
    }

#pragma unroll
    for (int rt = 0; rt < 2; rt++) {
        // h = silu(acc1 + b1) -> wave-private slab (bf16, XOR-swizzled)
#pragma unroll
        for (int ct = 0; ct < 8; ct++) {
            float b1v = b1[ct * 16 + c16];
#pragma unroll
            for (int i = 0; i < 4; i++) {
                float h = silu(acc1[rt][ct][i] + b1v);
                int hrow = quad * 4 + i;
                int boff = hrow * 256 + ((2 * (ct * 16 + c16)) ^ (hrow << 4));
                slab[boff >> 1] = __builtin_bit_cast(ushort, tobf(h));
            }
        }

        f32x4 acc2[8];
#pragma unroll
        for (int ct = 0; ct < 8; ct++) acc2[ct] = fz;

        // GEMM2: [16 x 128] @ w2 -> [16 x 128]
#pragma unroll
        for (int kb2 = 0; kb2 < 4; kb2++) {
            int boff = c16 * 256 + ((kb2 * 64 + quad * 16) ^ (c16 << 4));
            bf16x8 a2 = *(const bf16x8*)((const char*)slab + boff);
#pragma unroll
            for (int ct = 0; ct < 8; ct++) {
                bf16x8 bf = *(const bf16x8*)(w2p + ((size_t)((kb2 * 8 + ct) * 64 + lane)) * 8);
                acc2[ct] = mfma16(a2, bf, acc2[ct]);
            }
        }

        // bias + LayerNorm
        float sm[4] = {0,0,0,0}, sq[4] = {0,0,0,0};
#pragma unroll
        for (int ct = 0; ct < 8; ct++) {
            float b2v = b2[ct * 16 + c16];
#pragma unroll
            for (int i = 0; i < 4; i++) {
                float y = acc2[ct][i] + b2v;
                acc2[ct][i] = y; sm[i] += y; sq[i] += y * y;
            }
        }
#pragma unroll
        for (int m = 1; m < 16; m <<= 1)
#pragma unroll
            for (int i = 0; i < 4; i++) {
                sm[i] += __shfl_xor(sm[i], m, 64);
                sq[i] += __shfl_xor(sq[i], m, 64);
            }
        float mu[4], rstd[4];
#pragma unroll
        for (int i = 0; i < 4; i++) {
            mu[i] = sm[i] * (1.0f / 128.0f);
            float var = sq[i] * (1.0f / 128.0f) - mu[i] * mu[i];
            rstd[i] = __builtin_amdgcn_rsqf(var + 1e-5f);
        }

        // masked e_new -> slab (bf16, swizzled)
#pragma unroll
        for (int ct = 0; ct < 8; ct++) {
            int cg = ct * 16 + c16;
            float gv = g[cg], bev = beta[cg];
#pragma unroll
            for (int i = 0; i < 4; i++) {
                float e = (acc2[ct][i] - mu[i]) * rstd[i] * gv + bev;
                int row = quad * 4 + i;
                e = ((mask16[rt] >> row) & 1u) ? e : 0.0f;
                int boff = row * 256 + ((2 * cg) ^ (row << 4));
                slab[boff >> 1] = __builtin_bit_cast(ushort, tobf(e));
            }
        }

        // epilogue: E re-read (cache-hot), E_out = E + e_new, enew @ CSR pos
        const int rr = lane >> 2, seg = lane & 3;
        const int ps = wp0 + rt * 16 + rr;
        const int idr = (int)elist[ps];
#pragma unroll
        for (int j = 0; j < 4; j++) {
            int cb = (seg * 16 + j * 64) ^ (rr << 4);
            bf16x8 ev = *(const bf16x8*)((const char*)slab + rr * 256 + cb);
            size_t gb = (size_t)idr * D + seg * 8 + j * 32;
            float4 e0 = *(const float4*)(E + gb);
            float4 e1 = *(const float4*)(E + gb + 4);
            float4 o0, o1;
            o0.x = e0.x + (float)ev[0]; o0.y = e0.y + (float)ev[1];
            o0.z = e0.z + (float)ev[2]; o0.w = e0.w + (float)ev[3];
            o1.x = e1.x + (float)ev[4]; o1.y = e1.y + (float)ev[5];
            o1.z = e1.z + (float)ev[6]; o1.w = e1.w + (float)ev[7];
            *(float4*)(E_out + gb) = o0;
            *(float4*)(E_out + gb + 4) = o1;
            if (enewp)
                *(bf16x8*)(enewp + (size_t)ps * D + seg * 8 + j * 32) = ev;
        }
    }
}

// ---- aggregate: CSR-sequential mean of enew rows per node ----
__global__ void gnn_agg_kernel(const float* __restrict__ E, const float* __restrict__ E_out,
                               const ushort* __restrict__ enewp,
                               const unsigned* __restrict__ off, const unsigned* __restrict__ cnt,
                               const unsigned* __restrict__ elist, float* __restrict__ agg) {
    const int lane = threadIdx.x & 63;
    const int wid = (blockIdx.x * blockDim.x + threadIdx.x) >> 6;
    const int nw = (gridDim.x * blockDim.x) >> 6;
    for (int n = wid; n < TOTN; n += nw) {
        unsigned base = off[n], c = cnt[n];
        float a0 = 0.f, a1 = 0.f;
        unsigned e = 0;
        if (enewp) {
            const uint* rowp = (const uint*)(enewp + (size_t)base * D) + lane;
            while (e + 4 <= c) {
                uint v0 = rowp[0], v1 = rowp[64], v2 = rowp[128], v3 = rowp[192];
                a0 += bflo(v0) + bflo(v1) + bflo(v2) + bflo(v3);
                a1 += bfhi(v0) + bfhi(v1) + bfhi(v2) + bfhi(v3);
                rowp += 256; e += 4;
            }
            for (; e < c; e++) { uint v = *rowp; a0 += bflo(v); a1 += bfhi(v); rowp += 64; }
        } else {
            for (; e < c; e++) {
                unsigned id = elist[base + e];
                float2 eo = *(const float2*)(E_out + (size_t)id * D + lane * 2);
                float2 ee = *(const float2*)(E + (size_t)id * D + lane * 2);
                a0 += eo.x - ee.x; a1 += eo.y - ee.y;
            }
        }
        float rinv = 1.0f / (float)max(c, 1u);
        float2 outv; outv.x = a0 * rinv; outv.y = a1 * rinv;
        *(float2*)(agg + (size_t)n * D + lane * 2) = outv;
    }
}

// ---- node MLP: concat[V, agg] -> v_new; V_out = V + v_new; weights from L2 ----
__launch_bounds__(512)
__global__ void gnn_node_kernel(const float* __restrict__ V, const float* __restrict__ agg,
                                const float* __restrict__ b1, const float* __restrict__ b2,
                                const float* __restrict__ g, const float* __restrict__ beta,
                                const ushort* __restrict__ w1p, const ushort* __restrict__ w2p,
                                float* __restrict__ V_out) {
    __shared__ __align__(16) ushort lds[16384];  // 8 waves x 4KB slabs
    const int tid = threadIdx.x;
    const int wave = tid >> 6, lane = tid & 63;
    const int quad = lane >> 4, c16 = lane & 15;
    ushort* slab = lds + wave * 2048;

    const int wr0 = blockIdx.x * 256 + wave * 32;  // grid = ceil(TOTN/256)

    const float* pV[2]; const float* pG[2];
#pragma unroll
    for (int rt = 0; rt < 2; rt++) {
        int gc = min(wr0 + rt * 16 + c16, TOTN - 1);
        pV[rt] = V   + (size_t)gc * D;
        pG[rt] = agg + (size_t)gc * D;
    }

    f32x4 acc1[2][8];
    const f32x4 fz = {0.f, 0.f, 0.f, 0.f};
#pragma unroll
    for (int rt = 0; rt < 2; rt++)
#pragma unroll
        for (int ct = 0; ct < 8; ct++) acc1[rt][ct] = fz;

#pragma unroll
    for (int kb = 0; kb < 8; kb++) {
        const int part = kb >> 2;
        const int kloc = (kb & 3) * 32 + quad * 8;
        bf16x8 a[2];
#pragma unroll
        for (int rt = 0; rt < 2; rt++) {
            const float* p = (part == 0 ? pV[rt] : pG[rt]) + kloc;
            float4 x0 = *(const float4*)p;
            float4 x1 = *(const float4*)(p + 4);
            a[rt] = cvt8(x0, x1);
        }
#pragma unroll
        for (int ct = 0; ct < 8; ct++) {
            bf16x8 bf = *(const bf16x8*)(w1p + ((size_t)((kb * 8 + ct) * 64 + lane)) * 8);
            acc1[0][ct] = mfma16(a[0], bf, acc1[0][ct]);
            acc1[1][ct] = mfma16(a[1], bf, acc1[1][ct]);
        }
    }

#pragma unroll
    for (int rt = 0; rt < 2; rt++) {
#pragma unroll
        for (int ct = 0; ct < 8; ct++) {
            float b1v = b1[ct * 16 + c16];
#pragma unroll
            for (int i = 0; i < 4; i++) {
                float h = silu(acc1[rt][ct][i] + b1v);
                int hrow = quad * 4 + i;
                int boff = hrow * 256 + ((2 * (ct * 16 + c16)) ^ (hrow << 4));
                slab[boff >> 1] = __builtin_bit_cast(ushort, tobf(h));
            }
        }

        f32x4 acc2[8];
#pragma unroll
        for (int ct = 0; ct < 8; ct++) acc2[ct] = fz;
#pragma unroll
        for (int kb2 = 0; kb2 < 4; kb2++) {
            int boff = c16 * 256 + ((kb2 * 64 + quad * 16) ^ (c16 << 4));
            bf16x8 a2 = *(const bf16x8*)((const char*)slab + boff);
#pragma unroll
            for (int ct = 0; ct < 8; ct++) {
                bf16x8 bf = *(const bf16x8*)(w2p + ((size_t)((kb2 * 8 + ct) * 64 + lane)) * 8);
                acc2[ct] = mfma16(a2, bf, acc2[ct]);
            }
        }

        float sm[4] = {0,0,0,0}, sq[4] = {0,0,0,0};
#pragma unroll
        for (int ct = 0; ct < 8; ct++) {
            float b2v = b2[ct * 16 + c16];
#pragma unroll
            for (int i = 0; i < 4; i++) {
                float y = acc2[ct][i] + b2v;
                acc2[ct][i] = y; sm[i] += y; sq[i] += y * y;
            }
        }
#pragma unroll
        for (int m = 1; m < 16; m <<= 1)
#pragma unroll
            for (int i = 0; i < 4; i++) {
                sm[i] += __shfl_xor(sm[i], m, 64);
                sq[i] += __shfl_xor(sq[i], m, 64);
            }
        float mu[4], rstd[4];
#pragma unroll
        for (int i = 0; i < 4; i++) {
            mu[i] = sm[i] * (1.0f / 128.0f);
            float var = sq[i] * (1.0f / 128.0f) - mu[i] * mu[i];
            rstd[i] = __builtin_amdgcn_rsqf(var + 1e-5f);
        }
#pragma unroll
        for (int ct = 0; ct < 8; ct++) {
            int cg = ct * 16 + c16;
            float gv = g[cg], bev = beta[cg];
#pragma unroll
            for (int i = 0; i < 4; i++) {
                int geo = wr0 + rt * 16 + quad * 4 + i;
                if (geo < TOTN) {
                    float vn = (acc2[ct][i] - mu[i]) * rstd[i] * gv + bev;
                    V_out[(size_t)geo * D + cg] = V[(size_t)geo * D + cg] + vn;
                }
            }
        }
    }
}

extern "C" void kernel_launch(void* const* d_in, const int* in_sizes, int n_in,
                              void* d_out, int out_size, void* d_ws, size_t ws_size,
                              hipStream_t stream) {
    const float* V     = (const float*)d_in[0];
    const float* E     = (const float*)d_in[1];
    const int*   edges = (const int*)d_in[2];
    const float* fe_w1 = (const float*)d_in[3];
    const float* fe_b1 = (const float*)d_in[4];
    const float* fe_w2 = (const float*)d_in[5];
    const float* fe_b2 = (const float*)d_in[6];
    const float* fe_g  = (const float*)d_in[7];
    const float* fe_be = (const float*)d_in[8];
    const float* fn_w1 = (const float*)d_in[9];
    const float* fn_b1 = (const float*)d_in[10];
    const float* fn_w2 = (const float*)d_in[11];
    const float* fn_b2 = (const float*)d_in[12];
    const float* fn_g  = (const float*)d_in[13];
    const float* fn_be = (const float*)d_in[14];

    char* ws = (char*)d_ws;
    unsigned* cnt   = (unsigned*)(ws + WS_CNT);
    unsigned* off   = (unsigned*)(ws + WS_OFF);
    unsigned* cur   = (unsigned*)(ws + WS_CUR);
    unsigned* elist = (unsigned*)(ws + WS_ELIST);
    float*    agg   = (float*)(ws + WS_AGG);
    ushort*   w1e   = (ushort*)(ws + WS_W1E);
    ushort*   w2e   = (ushort*)(ws + WS_W2E);
    ushort*   w1n   = (ushort*)(ws + WS_W1N);
    ushort*   w2n   = (ushort*)(ws + WS_W2N);
    ushort*   enewp = (ws_size >= WS_NEED_ENEW) ? (ushort*)(ws + WS_ENEW) : (ushort*)nullptr;

    float* V_out = (float*)d_out;
    float* E_out = V_out + (size_t)TOTN * D;

    (void)hipMemsetAsync(cnt, 0, TOTN * sizeof(unsigned), stream);
    gnn_pack_kernel<<<28, 512, 0, stream>>>(fe_w1, fe_w2, fn_w1, fn_w2, w1e, w2e, w1n, w2n);
    gnn_cnt_kernel<<<8, 1024, 0, stream>>>(edges, cnt);
    gnn_scan_kernel<<<1, 1024, 0, stream>>>(cnt, off, cur);
    gnn_scatter_kernel<<<TOTE / 512, 512, 0, stream>>>(edges, cur, elist);
    gnn_edge_kernel<<<TOTE / 256, 512, 0, stream>>>(V, E, edges, elist, fe_b1, fe_b2,
                                                    fe_g, fe_be, w1e, w2e, enewp, E_out);
    gnn_agg_kernel<<<1024, 256, 0, stream>>>(E, E_out, enewp, off, cnt, elist, agg);
    gnn_node_kernel<<<(TOTN + 255) / 256, 512, 0, stream>>>(V, agg, fn_b1, fn_b2, fn_g, fn_be,
                                                            w1n, w2n, V_out);
}